// Round 8
// baseline (510.188 us; speedup 1.0000x reference)
//
#include <hip/hip_runtime.h>
#include <math.h>

// ReAttention round 12: kill the mix phase algebraically.
// r6-r11 bracket: k_mixsv pinned 77-93us by {~65-reg live set -> 4 waves/SIMD}
// x {S~ stream latency}; <64 unreachable without spill (r9: 405MB scratch).
// The mix phase is the structural cost -> remove it:
//  - PV head-swap: O1[g] = sum_h cw[g,h]*rv[h,n]*(S~_h @ v_g). Wave g keeps 8
//    per-head f32 accs (128 regs), MFMAs raw S~ frags vs v_g. No u, no sU,
//    no LDS, NO BARRIERS. cw*rv applied in epilogue (removes a f16 rounding).
//  - stats: Var(u) via Gram C[h,h'] = sum s^_h s^_h' (8x8): each wave computes
//    pairs with (h+h')&7==w from frags it already loads (v_fma_mix, under
//    MFMA shadow); rv*rv folded per-lane; atomicAdd to CMAT (dead-qkv space,
//    memset between k_sgen and k_mixsv). k_alpha: Eu2 = cw C cw^T / cnt.
//  - S~ layout -> per-head [b,h,n,m] (contiguous m): k_sgen stages per-head
//    sT2[8][32][40] + wave-local writeback (no 2nd-barrier dependency).
// B=8 N=1024 D=512 H=8 dh=64.
//
//  - conv bias cancels in train-mode BN (shifts mean only).
//  - attn'' = alpha_g*u_g + c_g ; u_g = sum_h conv_w[g,h]*S_h
//  - out_inner = alpha_g*O1 + c_g*vsum ; O1 = u @ v  (alpha-independent)

#define Bz 8
#define Nn 1024
#define Dd 512
#define Hh 8
#define DH 64
#define INNER 512
#define QW 1536
#define SCALE 0.125f
#define BN_EPS 1e-5f

typedef _Float16 __f16;
typedef __f16 f16x8 __attribute__((ext_vector_type(8)));
typedef float f32x4 __attribute__((ext_vector_type(4)));

#define MFMA16(a, b, c) __builtin_amdgcn_mfma_f32_16x16x32_f16((a), (b), (c), 0, 0, 0)

__device__ __forceinline__ unsigned short f2h(float f) {
  union { __f16 h; unsigned short s; } v;
  v.h = (__f16)f;  // v_cvt_f16_f32, RTN
  return v.s;
}
__device__ __forceinline__ float h2f(unsigned short s) {
  union { unsigned short s; __f16 h; } v;
  v.s = s;
  return (float)v.h;
}

// ws layout (bytes)
#define WB_XB 0u                       // 8,388,608  x fp16
#define WB_QKV 8388608u                // 25,165,824 q,k fp16 (stride QW)
#define WB_O1 0u                       // 16,777,216 fp32 (overlays XB+QKV head; both dead)
#define WB_CMAT 29360128u              // 256 B (dead qkv tail; memset after k_sgen)
#define WB_VT 33554432u                // 8,388,608  v^T fp16 [b,g,d,m]
#define WB_SG 41943040u                // 134,217,728 S~ fp16 PER-HEAD [b,h,n,m]
#define WB_O1BF WB_SG                  // 8,388,608 fp16, overlays dead S~
#define WB_WQT 176160768u              // 1,572,864
#define WB_WOT 177733632u              // 524,288
#define WB_RSUM 178257920u             // 262,144
#define WB_VSUM 178520064u             // 16,384
#define WB_AC 178536512u               // 64

// ---------------- x -> fp16 ------------------------------------------------
__global__ __launch_bounds__(256) void k_xbf(const float* __restrict__ X,
                                             unsigned short* __restrict__ XB) {
  const size_t i = ((size_t)blockIdx.x * 256 + threadIdx.x) * 8;
  float4 f0 = *(const float4*)(X + i);
  float4 f1 = *(const float4*)(X + i + 4);
  unsigned short o[8] = {f2h(f0.x), f2h(f0.y), f2h(f0.z), f2h(f0.w),
                         f2h(f1.x), f2h(f1.y), f2h(f1.z), f2h(f1.w)};
  *(uint4*)(XB + i) = *(uint4*)o;
}

// ---------------- transpose fp32 -> fp16: dst[C][R] = src[R][C]^T ----------
__global__ __launch_bounds__(256) void k_transpose(const float* __restrict__ src,
                                                   unsigned short* __restrict__ dst,
                                                   int R, int C) {
  __shared__ float tile[32][33];
  const int tc = blockIdx.x * 32, tr = blockIdx.y * 32;
  const int lx = threadIdx.x & 31, ly = threadIdx.x >> 5;
#pragma unroll
  for (int i = 0; i < 32; i += 8)
    tile[ly + i][lx] = src[(size_t)(tr + ly + i) * C + tc + lx];
  __syncthreads();
#pragma unroll
  for (int i = 0; i < 32; i += 8)
    dst[(size_t)(tc + ly + i) * R + tr + lx] = f2h(tile[lx][ly + i]);
}

// ---------------- K0: qkv = x @ w_qkv (fp16 MFMA) --------------------------
__global__ __launch_bounds__(256) void k_qkv(const unsigned short* __restrict__ XB,
                                             const unsigned short* __restrict__ WQT,
                                             unsigned short* __restrict__ qkv,
                                             unsigned short* __restrict__ vT) {
  extern __shared__ char smem[];
  unsigned short(*sA)[40] = (unsigned short(*)[40])smem;
  unsigned short(*sB)[40] = (unsigned short(*)[40])(smem + 128 * 40 * 2);
  unsigned short* sEp = (unsigned short*)smem;  // 128*136 after loop
  const int t = threadIdx.x;
  const int col0 = blockIdx.x * 128;
  const int row0 = blockIdx.y * 128;
  const bool isqk = (col0 < 2 * INNER);
  const int l = t & 63, w = t >> 6;
  const int wm = (w & 1) * 64, wn = (w >> 1) * 64;
  const int lm = l & 15, lq = l >> 4;
  const int srow = t >> 1, skc = (t & 1) * 16;
  f32x4 acc[4][4] = {};
  for (int k0 = 0; k0 < Dd; k0 += 32) {
    {
      const unsigned short* src = XB + (size_t)(row0 + srow) * Dd + k0 + skc;
      *(uint4*)&sA[srow][skc] = *(const uint4*)src;
      *(uint4*)&sA[srow][skc + 8] = *(const uint4*)(src + 8);
    }
    {
      const unsigned short* srcB = WQT + (size_t)(col0 + srow) * Dd + k0 + skc;
      *(uint4*)&sB[srow][skc] = *(const uint4*)srcB;
      *(uint4*)&sB[srow][skc + 8] = *(const uint4*)(srcB + 8);
    }
    __syncthreads();
    f16x8 af[4], bfr[4];
#pragma unroll
    for (int i = 0; i < 4; i++) af[i] = *(const f16x8*)&sA[wm + 16 * i + lm][lq * 8];
#pragma unroll
    for (int j = 0; j < 4; j++) bfr[j] = *(const f16x8*)&sB[wn + 16 * j + lm][lq * 8];
    if (isqk) {
#pragma unroll
      for (int i = 0; i < 4; i++)
#pragma unroll
        for (int j = 0; j < 4; j++) acc[i][j] = MFMA16(bfr[i], af[j], acc[i][j]);
    } else {
#pragma unroll
      for (int i = 0; i < 4; i++)
#pragma unroll
        for (int j = 0; j < 4; j++) acc[i][j] = MFMA16(af[i], bfr[j], acc[i][j]);
    }
    __syncthreads();
  }
  if (isqk) {
#pragma unroll
    for (int jc = 0; jc < 4; jc++)
#pragma unroll
      for (int ir = 0; ir < 4; ir++) {
        unsigned short us[4];
#pragma unroll
        for (int r = 0; r < 4; r++) us[r] = f2h(acc[jc][ir][r]);
        *(uint2*)&sEp[(wm + 16 * ir + lm) * 136 + wn + 16 * jc + 4 * lq] = *(uint2*)us;
      }
    __syncthreads();
    const int row = t >> 1, half = t & 1;
    const unsigned short* src = &sEp[row * 136 + half * 64];
    unsigned short* dst = qkv + (size_t)(row0 + row) * QW + col0 + half * 64;
#pragma unroll
    for (int c = 0; c < 8; c++) *(uint4*)(dst + c * 8) = *(const uint4*)(src + c * 8);
  } else {
#pragma unroll
    for (int ir = 0; ir < 4; ir++)
#pragma unroll
      for (int jc = 0; jc < 4; jc++) {
        unsigned short us[4];
#pragma unroll
        for (int r = 0; r < 4; r++) us[r] = f2h(acc[ir][jc][r]);
        *(uint2*)&sEp[(wn + 16 * jc + lm) * 136 + wm + 16 * ir + 4 * lq] = *(uint2*)us;
      }
    __syncthreads();
    const int row = t >> 1, half = t & 1;
    const int gd = col0 - 2 * INNER + row;
    const int bq = row0 >> 10, mseq0 = row0 & 1023;
    const unsigned short* src = &sEp[row * 136 + half * 64];
    unsigned short* dst =
        vT + (((size_t)(bq * Hh + (gd >> 6)) * DH + (gd & 63)) << 10) + mseq0 + half * 64;
#pragma unroll
    for (int c = 0; c < 8; c++) *(uint4*)(dst + c * 8) = *(const uint4*)(src + c * 8);
  }
}

// ---------------- k_vsum --------------------------------------------------
__global__ __launch_bounds__(256) void k_vsum(const unsigned short* __restrict__ vT,
                                              float* __restrict__ vsum) {
  const int bg = blockIdx.x;
  const int d = threadIdx.x >> 2, qq = threadIdx.x & 3;
  __shared__ float red[64][4];
  const unsigned short* p = vT + ((size_t)bg * DH + d) * Nn + qq * 256;
  float s = 0.f;
  for (int m = 0; m < 256; m += 4) {
    uint2 rr = *(const uint2*)(p + m);
    s += h2f((unsigned short)(rr.x & 0xffff)) + h2f((unsigned short)(rr.x >> 16)) +
         h2f((unsigned short)(rr.y & 0xffff)) + h2f((unsigned short)(rr.y >> 16));
  }
  red[d][qq] = s;
  __syncthreads();
  if (threadIdx.x < 64)
    vsum[(size_t)bg * DH + threadIdx.x] =
        red[threadIdx.x][0] + red[threadIdx.x][1] + red[threadIdx.x][2] + red[threadIdx.x][3];
}

// ---------------- kA: S~ PER-HEAD [b,h,n,m] + row-sum partials --------------
// grid (b=8, nt=32, mh=2); block 512 = 8 waves, wave w = head w.
// sT2 is per-head: wave w writes+reads only sT2[w] -> wave-local writeback,
// single barrier protects sK restage only.
__global__ __launch_bounds__(512, 2) void k_sgen(const unsigned short* __restrict__ qkv,
                                                 unsigned short* __restrict__ Sg,
                                                 float* __restrict__ rsum) {
  __shared__ unsigned short sK[8 * 32 * 72];    // 36,864 B
  __shared__ unsigned short sT2[8][32][40];     // 20,480 B [h][n][m], 80B rows (16B-aligned)
  const int b = blockIdx.x;
  const int n0 = blockIdx.y * 32;
  const int mh = blockIdx.z;
  const int t = threadIdx.x;
  const int w = t >> 6, l = t & 63;
  const int lm = l & 15, lq = l >> 4;
  f16x8 qf[2][2];
#pragma unroll
  for (int i = 0; i < 2; i++) {
    const unsigned short* qp =
        qkv + (size_t)(b * Nn + n0 + 16 * i + lm) * QW + w * DH + lq * 8;
    qf[i][0] = *(const f16x8*)qp;
    qf[i][1] = *(const f16x8*)(qp + 32);
  }
  float psum[2] = {0.f, 0.f};
  for (int it = 0; it < 16; it++) {
    const int m0 = mh * 512 + it * 32;
    {  // stage K: all heads, 32m x 64d, [h][m][72]; uint4 = 8 shorts
#pragma unroll
      for (int s = 0; s < 4; s++) {
        const int c = t + s * 512;
        const int hh = c >> 8, mm = (c >> 3) & 31, qq = c & 7;
        *(uint4*)&sK[(hh * 32 + mm) * 72 + qq * 8] = *(const uint4*)(
            qkv + (size_t)(b * Nn + m0 + mm) * QW + INNER + hh * DH + qq * 8);
      }
    }
    __syncthreads();
    f32x4 lac[2][2] = {};
#pragma unroll
    for (int jm = 0; jm < 2; jm++) {
      f16x8 ka0 = *(const f16x8*)&sK[(w * 32 + 16 * jm + lm) * 72 + lq * 8];
      f16x8 ka1 = *(const f16x8*)&sK[(w * 32 + 16 * jm + lm) * 72 + 32 + lq * 8];
#pragma unroll
      for (int i = 0; i < 2; i++) {
        lac[i][jm] = MFMA16(ka0, qf[i][0], lac[i][jm]);
        lac[i][jm] = MFMA16(ka1, qf[i][1], lac[i][jm]);
      }
    }
#pragma unroll
    for (int i = 0; i < 2; i++)
#pragma unroll
      for (int jm = 0; jm < 2; jm++) {
        unsigned short us[4];
#pragma unroll
        for (int r = 0; r < 4; r++) {
          float e = __expf(lac[i][jm][r] * SCALE);
          psum[i] += e;
          us[r] = f2h(e);
        }
        *(uint2*)&sT2[w][16 * i + lm][16 * jm + 4 * lq] = *(uint2*)us;
      }
    {  // wave-local writeback: 32 rows x 64B, 2 lanes/row (lgkmcnt, no barrier)
      const int row = l >> 1, half = l & 1;
      const unsigned short* src = &sT2[w][row][half * 16];
      unsigned short* dst =
          Sg + ((size_t)(b * Hh + w) * Nn + n0 + row) * Nn + m0 + half * 16;
      *(uint4*)dst = *(const uint4*)src;
      *(uint4*)(dst + 8) = *(const uint4*)(src + 8);
    }
    __syncthreads();  // protect sK restage (sT2[w] is wave-private)
  }
#pragma unroll
  for (int i = 0; i < 2; i++) {
    psum[i] += __shfl_xor(psum[i], 16);
    psum[i] += __shfl_xor(psum[i], 32);
  }
  if (lq == 0) {
    atomicAdd(&rsum[(size_t)(b * Hh + w) * Nn + n0 + lm], psum[0]);
    atomicAdd(&rsum[(size_t)(b * Hh + w) * Nn + n0 + 16 + lm], psum[1]);
  }
}

// ---------------- kB: head-swapped PV + Gram stats (no LDS, no barriers) ---
// grid (b=8, nt=64); block 512 = 8 waves; wave w = group g.
// acc[h][j]: per-head f32 accumulators; epilogue applies cw[g,h]*rv[h,n].
// Gram pairs (h,(w-h)&7) with h2>=h: ~4-5/wave, each once per block.
__global__ __launch_bounds__(512, 2) void k_mixsv(const unsigned short* __restrict__ Sg,
                                                  const unsigned short* __restrict__ vT,
                                                  const float* __restrict__ rsum,
                                                  const float* __restrict__ conv_w,
                                                  float* __restrict__ O1,
                                                  float* __restrict__ cmat) {
  const int b = blockIdx.x;  // b fastest -> XCD-pinned vT/S~ slices in L2
  const int n0 = blockIdx.y * 16;
  const int t = threadIdx.x;
  const int w = t >> 6, l = t & 63;
  const int lm = l & 15, lq = l >> 4;
  const unsigned short* sb[8];
#pragma unroll
  for (int h = 0; h < 8; h++)
    sb[h] = Sg + ((size_t)(b * Hh + h) * Nn + n0 + lm) * Nn + lq * 8;
  const unsigned short* vbase = vT + (((size_t)(b * Hh + w) * DH + lm) << 10) + lq * 8;
  f32x4 acc[8][4] = {};
  float gam[8] = {0.f, 0.f, 0.f, 0.f, 0.f, 0.f, 0.f, 0.f};
  for (int it = 0; it < 16; it++) {
    const int m0 = it * 64;
    f16x8 va[4], vb[4];
#pragma unroll
    for (int j = 0; j < 4; j++) {
      va[j] = *(const f16x8*)(vbase + (j << 14) + m0);
      vb[j] = *(const f16x8*)(vbase + (j << 14) + m0 + 32);
    }
#pragma unroll
    for (int h = 0; h < 8; h++) {
      f16x8 a0 = *(const f16x8*)(sb[h] + m0);
      f16x8 a1 = *(const f16x8*)(sb[h] + m0 + 32);
#pragma unroll
      for (int j = 0; j < 4; j++) {
        acc[h][j] = MFMA16(a0, va[j], acc[h][j]);
        acc[h][j] = MFMA16(a1, vb[j], acc[h][j]);
      }
    }
    // Gram partials: raw e-products (rv folded in epilogue); L1-hot reloads.
#pragma unroll
    for (int h = 0; h < 8; h++) {
      const int h2 = (w - h) & 7;
      if (h2 >= h) {
        f16x8 x0 = *(const f16x8*)(sb[h] + m0);
        f16x8 x1 = *(const f16x8*)(sb[h] + m0 + 32);
        f16x8 y0 = *(const f16x8*)(sb[h2] + m0);
        f16x8 y1 = *(const f16x8*)(sb[h2] + m0 + 32);
        float g = gam[h];
#pragma unroll
        for (int s = 0; s < 8; s++) {
          g = fmaf((float)x0[s], (float)y0[s], g);  // v_fma_mix_f32
          g = fmaf((float)x1[s], (float)y1[s], g);
        }
        gam[h] = g;
      }
    }
  }
  // ---- C-matrix: scale by rv[h,lm]*rv[h2,lm], wave-reduce, one atomic ----
  {
    float rvl[8];
#pragma unroll
    for (int h = 0; h < 8; h++)
      rvl[h] = 1.0f / rsum[(size_t)(b * Hh + h) * Nn + n0 + lm];
#pragma unroll
    for (int h = 0; h < 8; h++) {
      const int h2 = (w - h) & 7;
      if (h2 >= h) {
        float g = gam[h] * rvl[h] * rvl[h2];
#pragma unroll
        for (int off = 32; off; off >>= 1) g += __shfl_down(g, off);
        if (l == 0) atomicAdd(&cmat[h * 8 + h2], g);
      }
    }
  }
  // ---- O1 epilogue: O1 = sum_h cw[g,h]*rv[h,n]*acc[h] ----
  float cw8[8];
#pragma unroll
  for (int h = 0; h < 8; h++) cw8[h] = conv_w[w * 8 + h];
  float sc[8][4];
#pragma unroll
  for (int h = 0; h < 8; h++) {
    float4 rr = *(const float4*)&rsum[(size_t)(b * Hh + h) * Nn + n0 + lq * 4];
    sc[h][0] = cw8[h] / rr.x;
    sc[h][1] = cw8[h] / rr.y;
    sc[h][2] = cw8[h] / rr.z;
    sc[h][3] = cw8[h] / rr.w;
  }
#pragma unroll
  for (int j = 0; j < 4; j++)
#pragma unroll
    for (int r = 0; r < 4; r++) {
      float o = 0.f;
#pragma unroll
      for (int h = 0; h < 8; h++) o = fmaf(sc[h][r], acc[h][j][r], o);
      O1[((size_t)(b * Hh + w) * Nn + n0 + lq * 4 + r) * DH + 16 * j + lm] = o;
    }
}

// ---------------- K3: alpha/const ------------------------------------------
// E[u] analytic; E[u^2] = cw_g C cw_g^T / cnt  (C upper-triangular in cmat).
__global__ void k_alpha(const float* __restrict__ cmat, const float* __restrict__ conv_w,
                        const float* __restrict__ bn_gamma,
                        const float* __restrict__ bn_beta, float* __restrict__ ac) {
  const int g = threadIdx.x;
  if (g < 8) {
    const float cnt = (float)Bz * (float)Nn * (float)Nn;
    float scw = 0.f;
#pragma unroll
    for (int h = 0; h < 8; h++) scw += conv_w[g * 8 + h];
    float Eu = scw * (1.0f / (float)Nn);
    float Eu2 = 0.f;
#pragma unroll
    for (int h = 0; h < 8; h++)
#pragma unroll
      for (int h2 = h; h2 < 8; h2++) {
        float mul = (h == h2) ? 1.f : 2.f;
        Eu2 += mul * conv_w[g * 8 + h] * conv_w[g * 8 + h2] * cmat[h * 8 + h2];
      }
    Eu2 /= cnt;
    float inv = rsqrtf(Eu2 - Eu * Eu + BN_EPS);
    float alpha = bn_gamma[g] * inv;
    ac[g] = alpha;
    ac[8 + g] = bn_beta[g] - Eu * alpha;
  }
}

// ---------------- k_o1aff: O1hf = fp16(alpha*O1 + c*vsum) ------------------
__global__ __launch_bounds__(256) void k_o1aff(const float* __restrict__ O1,
                                               const float* __restrict__ vsum,
                                               const float* __restrict__ ac,
                                               unsigned short* __restrict__ O1BF) {
  const size_t i4 = ((size_t)blockIdx.x * 256 + threadIdx.x) * 4;
  const int bg = (int)(i4 >> 16);
  const int g = bg & 7;
  const int d = (int)(i4 & 63);
  float4 a = *(const float4*)(O1 + i4);
  float4 v = *(const float4*)(vsum + (size_t)bg * DH + d);
  const float al = ac[g], cc = ac[8 + g];
  unsigned short o[4] = {f2h(al * a.x + cc * v.x), f2h(al * a.y + cc * v.y),
                         f2h(al * a.z + cc * v.z), f2h(al * a.w + cc * v.w)};
  *(uint2*)(O1BF + i4) = *(uint2*)o;
}

// ---------------- K4: out = O1hf @ w_out + b_out (fp16 MFMA) ---------------
__global__ __launch_bounds__(256) void k_out(const unsigned short* __restrict__ O1BF,
                                             const unsigned short* __restrict__ WOT,
                                             const float* __restrict__ bout,
                                             float* __restrict__ out) {
  __shared__ unsigned short sA[128][40];
  __shared__ unsigned short sB[128][40];
  const int t = threadIdx.x;
  const int col0 = blockIdx.x * 128, row0 = blockIdx.y * 128;
  const int l = t & 63, w = t >> 6;
  const int wm = (w & 1) * 64, wn = (w >> 1) * 64;
  const int lm = l & 15, lq = l >> 4;
  const int srow = t >> 1, skc = (t & 1) * 16;
  const int b = row0 >> 10;
  const int nn = (row0 + srow) & 1023;
  f32x4 acc[4][4] = {};
  for (int k0 = 0; k0 < INNER; k0 += 32) {
    {
      const int k = k0 + skc;
      const int g = k >> 6, dd = k & 63;
      const unsigned short* src = O1BF + ((size_t)(b * Hh + g) * Nn + nn) * DH + dd;
      *(uint4*)&sA[srow][skc] = *(const uint4*)src;
      *(uint4*)&sA[srow][skc + 8] = *(const uint4*)(src + 8);
    }
    {
      const unsigned short* srcB = WOT + (size_t)(col0 + srow) * INNER + k0 + skc;
      *(uint4*)&sB[srow][skc] = *(const uint4*)srcB;
      *(uint4*)&sB[srow][skc + 8] = *(const uint4*)(srcB + 8);
    }
    __syncthreads();
    f16x8 af[4], bfr[4];
#pragma unroll
    for (int i = 0; i < 4; i++) af[i] = *(const f16x8*)&sA[wm + 16 * i + lm][lq * 8];
#pragma unroll
    for (int j = 0; j < 4; j++) bfr[j] = *(const f16x8*)&sB[wn + 16 * j + lm][lq * 8];
#pragma unroll
    for (int i = 0; i < 4; i++)
#pragma unroll
      for (int j = 0; j < 4; j++) acc[i][j] = MFMA16(af[i], bfr[j], acc[i][j]);
    __syncthreads();
  }
#pragma unroll
  for (int j = 0; j < 4; j++) {
    const int col = col0 + wn + 16 * j + lm;
    const float bo = bout[col];
#pragma unroll
    for (int i = 0; i < 4; i++) {
      const int rbase = row0 + wm + 16 * i + lq * 4;
#pragma unroll
      for (int r = 0; r < 4; r++) out[(size_t)(rbase + r) * Dd + col] = acc[i][j][r] + bo;
    }
  }
}

extern "C" void kernel_launch(void* const* d_in, const int* in_sizes, int n_in,
                              void* d_out, int out_size, void* d_ws, size_t ws_size,
                              hipStream_t stream) {
  const float* x = (const float*)d_in[0];
  const float* w_qkv = (const float*)d_in[1];
  const float* conv_w = (const float*)d_in[2];
  // d_in[3] = conv_b : cancels in train-mode BN.
  const float* bn_gamma = (const float*)d_in[4];
  const float* bn_beta = (const float*)d_in[5];
  const float* w_out = (const float*)d_in[6];
  const float* b_out = (const float*)d_in[7];
  char* ws = (char*)d_ws;
  unsigned short* XB = (unsigned short*)(ws + WB_XB);
  unsigned short* QKV = (unsigned short*)(ws + WB_QKV);
  unsigned short* VT = (unsigned short*)(ws + WB_VT);
  unsigned short* SG = (unsigned short*)(ws + WB_SG);
  unsigned short* WQT = (unsigned short*)(ws + WB_WQT);
  unsigned short* WOT = (unsigned short*)(ws + WB_WOT);
  float* O1 = (float*)(ws + WB_O1);
  unsigned short* O1BF = (unsigned short*)(ws + WB_O1BF);
  float* RSUM = (float*)(ws + WB_RSUM);
  float* VSUM = (float*)(ws + WB_VSUM);
  float* CMAT = (float*)(ws + WB_CMAT);
  float* AC = (float*)(ws + WB_AC);

  hipMemsetAsync(RSUM, 0, 262144, stream);
  k_xbf<<<2048, 256, 0, stream>>>(x, XB);
  k_transpose<<<dim3(48, 16), 256, 0, stream>>>(w_qkv, WQT, 512, 1536);
  k_transpose<<<dim3(16, 16), 256, 0, stream>>>(w_out, WOT, 512, 512);
  k_qkv<<<dim3(12, 64), 256, 34816, stream>>>(XB, WQT, QKV, VT);
  k_vsum<<<64, 256, 0, stream>>>(VT, VSUM);
  k_sgen<<<dim3(8, 32, 2), 512, 0, stream>>>(QKV, SG, RSUM);
  hipMemsetAsync(CMAT, 0, 256, stream);  // dead-qkv region; stream-ordered after k_sgen
  k_mixsv<<<dim3(8, 64), 512, 0, stream>>>(SG, VT, RSUM, conv_w, O1, CMAT);
  k_alpha<<<1, 64, 0, stream>>>(CMAT, conv_w, bn_gamma, bn_beta, AC);
  k_o1aff<<<4096, 256, 0, stream>>>(O1, VSUM, AC, O1BF);
  k_out<<<dim3(4, 64), 256, 0, stream>>>(O1BF, WOT, b_out, (float*)d_out);
}

// Round 9
// 274.176 us; speedup vs baseline: 1.8608x; 1.8608x over previous
//
#include <hip/hip_runtime.h>
#include <math.h>

// ReAttention round 13: consolidation. r6 pipeline restored byte-for-byte
// (the only proven-81.5us k_mixsv; 6-variant bracket r6-r12 shows 77-81us is
// its floor and every structural alternative regresses), plus ONE safe win:
// k_o1aff fused into k_out's A-staging (saves a 33.5MB-read/8.4MB-write pass
// + a launch gap; affine coefficients are uniform per 16-element A-chunk).
// B=8 N=1024 D=512 H=8 dh=64.
//
//  - conv bias cancels in train-mode BN (shifts mean only).
//  - attn'' = alpha_g*u_g + c_g ; u_g = sum_h conv_w[g,h]*S_h
//  - out_inner = alpha_g*O1 + c_g*vsum ; O1 = u @ v  (alpha-independent)
//  - S~ stored UNNORMALIZED fp16, head-interleaved: el ((b*N+n)*N+m)*8+h

#define Bz 8
#define Nn 1024
#define Dd 512
#define Hh 8
#define DH 64
#define INNER 512
#define QW 1536
#define SCALE 0.125f
#define BN_EPS 1e-5f

typedef _Float16 __f16;
typedef __f16 f16x8 __attribute__((ext_vector_type(8)));
typedef float f32x4 __attribute__((ext_vector_type(4)));

#define MFMA16(a, b, c) __builtin_amdgcn_mfma_f32_16x16x32_f16((a), (b), (c), 0, 0, 0)

__device__ __forceinline__ unsigned short f2h(float f) {
  union { __f16 h; unsigned short s; } v;
  v.h = (__f16)f;  // v_cvt_f16_f32, RTN
  return v.s;
}
__device__ __forceinline__ float h2f(unsigned short s) {
  union { unsigned short s; __f16 h; } v;
  v.s = s;
  return (float)v.h;
}

// ws layout (bytes)
#define WB_XB 0u                       // 8,388,608  x fp16
#define WB_QKV 8388608u                // 25,165,824 q,k fp16 (stride QW)
#define WB_O1 0u                       // 16,777,216 fp32 (overlays XB + head of QKV; both dead)
#define WB_VT 33554432u                // 8,388,608  v^T fp16 [b,g,d,m]
#define WB_SG 41943040u                // 134,217,728 S~ fp16 [b,n,m,h]
#define WB_WQT 176160768u              // 1,572,864
#define WB_WOT 177733632u              // 524,288
#define WB_RSUM 178257920u             // 262,144
#define WB_VSUM 178520064u             // 16,384
#define WB_STATS 178536448u            // 64
#define WB_AC 178536512u               // 64

// ---------------- x -> fp16 ------------------------------------------------
__global__ __launch_bounds__(256) void k_xbf(const float* __restrict__ X,
                                             unsigned short* __restrict__ XB) {
  const size_t i = ((size_t)blockIdx.x * 256 + threadIdx.x) * 8;
  float4 f0 = *(const float4*)(X + i);
  float4 f1 = *(const float4*)(X + i + 4);
  unsigned short o[8] = {f2h(f0.x), f2h(f0.y), f2h(f0.z), f2h(f0.w),
                         f2h(f1.x), f2h(f1.y), f2h(f1.z), f2h(f1.w)};
  *(uint4*)(XB + i) = *(uint4*)o;
}

// ---------------- transpose fp32 -> fp16: dst[C][R] = src[R][C]^T ----------
__global__ __launch_bounds__(256) void k_transpose(const float* __restrict__ src,
                                                   unsigned short* __restrict__ dst,
                                                   int R, int C) {
  __shared__ float tile[32][33];
  const int tc = blockIdx.x * 32, tr = blockIdx.y * 32;
  const int lx = threadIdx.x & 31, ly = threadIdx.x >> 5;
#pragma unroll
  for (int i = 0; i < 32; i += 8)
    tile[ly + i][lx] = src[(size_t)(tr + ly + i) * C + tc + lx];
  __syncthreads();
#pragma unroll
  for (int i = 0; i < 32; i += 8)
    dst[(size_t)(tc + ly + i) * R + tr + lx] = f2h(tile[lx][ly + i]);
}

// ---------------- K0: qkv = x @ w_qkv (fp16 MFMA) --------------------------
__global__ __launch_bounds__(256) void k_qkv(const unsigned short* __restrict__ XB,
                                             const unsigned short* __restrict__ WQT,
                                             unsigned short* __restrict__ qkv,
                                             unsigned short* __restrict__ vT) {
  extern __shared__ char smem[];
  unsigned short(*sA)[40] = (unsigned short(*)[40])smem;
  unsigned short(*sB)[40] = (unsigned short(*)[40])(smem + 128 * 40 * 2);
  unsigned short* sEp = (unsigned short*)smem;  // 128*136 after loop
  const int t = threadIdx.x;
  const int col0 = blockIdx.x * 128;
  const int row0 = blockIdx.y * 128;
  const bool isqk = (col0 < 2 * INNER);
  const int l = t & 63, w = t >> 6;
  const int wm = (w & 1) * 64, wn = (w >> 1) * 64;
  const int lm = l & 15, lq = l >> 4;
  const int srow = t >> 1, skc = (t & 1) * 16;
  f32x4 acc[4][4] = {};
  for (int k0 = 0; k0 < Dd; k0 += 32) {
    {
      const unsigned short* src = XB + (size_t)(row0 + srow) * Dd + k0 + skc;
      *(uint4*)&sA[srow][skc] = *(const uint4*)src;
      *(uint4*)&sA[srow][skc + 8] = *(const uint4*)(src + 8);
    }
    {
      const unsigned short* srcB = WQT + (size_t)(col0 + srow) * Dd + k0 + skc;
      *(uint4*)&sB[srow][skc] = *(const uint4*)srcB;
      *(uint4*)&sB[srow][skc + 8] = *(const uint4*)(srcB + 8);
    }
    __syncthreads();
    f16x8 af[4], bfr[4];
#pragma unroll
    for (int i = 0; i < 4; i++) af[i] = *(const f16x8*)&sA[wm + 16 * i + lm][lq * 8];
#pragma unroll
    for (int j = 0; j < 4; j++) bfr[j] = *(const f16x8*)&sB[wn + 16 * j + lm][lq * 8];
    if (isqk) {
#pragma unroll
      for (int i = 0; i < 4; i++)
#pragma unroll
        for (int j = 0; j < 4; j++) acc[i][j] = MFMA16(bfr[i], af[j], acc[i][j]);
    } else {
#pragma unroll
      for (int i = 0; i < 4; i++)
#pragma unroll
        for (int j = 0; j < 4; j++) acc[i][j] = MFMA16(af[i], bfr[j], acc[i][j]);
    }
    __syncthreads();
  }
  if (isqk) {
#pragma unroll
    for (int jc = 0; jc < 4; jc++)
#pragma unroll
      for (int ir = 0; ir < 4; ir++) {
        unsigned short us[4];
#pragma unroll
        for (int r = 0; r < 4; r++) us[r] = f2h(acc[jc][ir][r]);
        *(uint2*)&sEp[(wm + 16 * ir + lm) * 136 + wn + 16 * jc + 4 * lq] = *(uint2*)us;
      }
    __syncthreads();
    const int row = t >> 1, half = t & 1;
    const unsigned short* src = &sEp[row * 136 + half * 64];
    unsigned short* dst = qkv + (size_t)(row0 + row) * QW + col0 + half * 64;
#pragma unroll
    for (int c = 0; c < 8; c++) *(uint4*)(dst + c * 8) = *(const uint4*)(src + c * 8);
  } else {
#pragma unroll
    for (int ir = 0; ir < 4; ir++)
#pragma unroll
      for (int jc = 0; jc < 4; jc++) {
        unsigned short us[4];
#pragma unroll
        for (int r = 0; r < 4; r++) us[r] = f2h(acc[ir][jc][r]);
        *(uint2*)&sEp[(wn + 16 * jc + lm) * 136 + wm + 16 * ir + 4 * lq] = *(uint2*)us;
      }
    __syncthreads();
    const int row = t >> 1, half = t & 1;
    const int gd = col0 - 2 * INNER + row;
    const int bq = row0 >> 10, mseq0 = row0 & 1023;
    const unsigned short* src = &sEp[row * 136 + half * 64];
    unsigned short* dst =
        vT + (((size_t)(bq * Hh + (gd >> 6)) * DH + (gd & 63)) << 10) + mseq0 + half * 64;
#pragma unroll
    for (int c = 0; c < 8; c++) *(uint4*)(dst + c * 8) = *(const uint4*)(src + c * 8);
  }
}

// ---------------- k_vsum --------------------------------------------------
__global__ __launch_bounds__(256) void k_vsum(const unsigned short* __restrict__ vT,
                                              float* __restrict__ vsum) {
  const int bg = blockIdx.x;
  const int d = threadIdx.x >> 2, qq = threadIdx.x & 3;
  __shared__ float red[64][4];
  const unsigned short* p = vT + ((size_t)bg * DH + d) * Nn + qq * 256;
  float s = 0.f;
  for (int m = 0; m < 256; m += 4) {
    uint2 rr = *(const uint2*)(p + m);
    s += h2f((unsigned short)(rr.x & 0xffff)) + h2f((unsigned short)(rr.x >> 16)) +
         h2f((unsigned short)(rr.y & 0xffff)) + h2f((unsigned short)(rr.y >> 16));
  }
  red[d][qq] = s;
  __syncthreads();
  if (threadIdx.x < 64)
    vsum[(size_t)bg * DH + threadIdx.x] =
        red[threadIdx.x][0] + red[threadIdx.x][1] + red[threadIdx.x][2] + red[threadIdx.x][3];
}

// ---------------- kA: S~ head-interleaved + row-sum partials ---------------
// grid (b=8, nt=32, mh=2); block 512 = 8 waves, wave w = head w.  (r6 exact)
__global__ __launch_bounds__(512, 2) void k_sgen(const unsigned short* __restrict__ qkv,
                                                 unsigned short* __restrict__ Sg,
                                                 float* __restrict__ rsum) {
  __shared__ unsigned short sK[8 * 32 * 72];  // 36,864 B
  __shared__ unsigned short sT[32 * 264];     // 16,896 B  [n][m*8+h], pad 8
  const int b = blockIdx.x;
  const int n0 = blockIdx.y * 32;
  const int mh = blockIdx.z;
  const int t = threadIdx.x;
  const int w = t >> 6, l = t & 63;
  const int lm = l & 15, lq = l >> 4;
  f16x8 qf[2][2];
#pragma unroll
  for (int i = 0; i < 2; i++) {
    const unsigned short* qp =
        qkv + (size_t)(b * Nn + n0 + 16 * i + lm) * QW + w * DH + lq * 8;
    qf[i][0] = *(const f16x8*)qp;
    qf[i][1] = *(const f16x8*)(qp + 32);
  }
  float psum[2] = {0.f, 0.f};
  for (int it = 0; it < 16; it++) {
    const int m0 = mh * 512 + it * 32;
    {  // stage K: all heads, 32m x 64d, [h][m][72]; uint4 = 8 shorts
#pragma unroll
      for (int s = 0; s < 4; s++) {
        const int c = t + s * 512;
        const int hh = c >> 8, mm = (c >> 3) & 31, qq = c & 7;
        *(uint4*)&sK[(hh * 32 + mm) * 72 + qq * 8] = *(const uint4*)(
            qkv + (size_t)(b * Nn + m0 + mm) * QW + INNER + hh * DH + qq * 8);
      }
    }
    __syncthreads();
    f32x4 lac[2][2] = {};
#pragma unroll
    for (int jm = 0; jm < 2; jm++) {
      f16x8 ka0 = *(const f16x8*)&sK[(w * 32 + 16 * jm + lm) * 72 + lq * 8];
      f16x8 ka1 = *(const f16x8*)&sK[(w * 32 + 16 * jm + lm) * 72 + 32 + lq * 8];
#pragma unroll
      for (int i = 0; i < 2; i++) {
        lac[i][jm] = MFMA16(ka0, qf[i][0], lac[i][jm]);
        lac[i][jm] = MFMA16(ka1, qf[i][1], lac[i][jm]);
      }
    }
#pragma unroll
    for (int i = 0; i < 2; i++)
#pragma unroll
      for (int jm = 0; jm < 2; jm++)
#pragma unroll
        for (int r = 0; r < 4; r++) {
          float e = __expf(lac[i][jm][r] * SCALE);
          psum[i] += e;
          sT[(16 * i + lm) * 264 + (16 * jm + 4 * lq + r) * 8 + w] = f2h(e);
        }
    __syncthreads();
    {  // coop store: 32 rows x 512B, fully coalesced
      const int row = t >> 4, ck = t & 15;
      unsigned short* dst =
          Sg + (((size_t)(b * Nn + n0 + row) << 10) + m0) * 8 + ck * 16;
      const unsigned short* src = &sT[row * 264 + ck * 16];
      *(uint4*)dst = *(const uint4*)src;
      *(uint4*)(dst + 8) = *(const uint4*)(src + 8);
    }
  }
#pragma unroll
  for (int i = 0; i < 2; i++) {
    psum[i] += __shfl_xor(psum[i], 16);
    psum[i] += __shfl_xor(psum[i], 32);
  }
  if (lq == 0) {
    atomicAdd(&rsum[(size_t)(b * Hh + w) * Nn + n0 + lm], psum[0]);
    atomicAdd(&rsum[(size_t)(b * Hh + w) * Nn + n0 + 16 + lm], psum[1]);
  }
}

// ---------------- kB: mix + stats + S@V (r6 exact: 81.5us, VGPR=60) --------
// grid (b=8, nt=64); block 512 = 8 waves; wave w = group g.
__global__ __launch_bounds__(512, 2) void k_mixsv(const unsigned short* __restrict__ Sg,
                                                  const unsigned short* __restrict__ vT,
                                                  const float* __restrict__ rsum,
                                                  const float* __restrict__ conv_w,
                                                  float* __restrict__ O1,
                                                  float* __restrict__ stats) {
  __shared__ unsigned short sU[8][16][68];  // 17,408 B
  __shared__ float sRed[8][16];
  const int b = blockIdx.x;  // b fastest -> XCD-pinned vT slice in L2
  const int n0 = blockIdx.y * 16;
  const int t = threadIdx.x;
  const int w = t >> 6, l = t & 63;
  const int lm = l & 15, lq = l >> 4;
  const int mxn = t >> 5, mxm = (t & 31) * 2;
  float cw[64];
#pragma unroll
  for (int i = 0; i < 64; i++) cw[i] = conv_w[i];  // uniform -> SGPRs
  float rv[8];
#pragma unroll
  for (int h = 0; h < 8; h++) rv[h] = 1.0f / rsum[(size_t)(b * Hh + h) * Nn + n0 + mxn];
  const unsigned short* sNp = Sg + ((size_t)(b * Nn + n0 + mxn) << 13);  // row base *8192
  f32x4 oacc[4] = {};
  float su[8] = {}, su2[8] = {};
  uint4 c0, c1;
  {
    const unsigned short* p = sNp + (mxm << 3);
    c0 = *(const uint4*)p;
    c1 = *(const uint4*)(p + 8);
  }
  for (int it = 0; it < 16; it++) {
    uint4 nx0, nx1;
    if (it < 15) {  // shallow prefetch (2 uint4 live extra — no spill at cap 256)
      const unsigned short* p = sNp + ((size_t)((it + 1) * 64 + mxm) << 3);
      nx0 = *(const uint4*)p;
      nx1 = *(const uint4*)(p + 8);
    }
    {  // mix: 2 m-positions x 8 heads from c0/c1
      const unsigned* pe = (const unsigned*)&c0;  // m even, heads 0..7
      const unsigned* po = (const unsigned*)&c1;  // m odd,  heads 0..7
      float sx[8], sy[8];
#pragma unroll
      for (int hp = 0; hp < 4; hp++) {
        sx[2 * hp] = h2f((unsigned short)(pe[hp] & 0xffff)) * rv[2 * hp];
        sx[2 * hp + 1] = h2f((unsigned short)(pe[hp] >> 16)) * rv[2 * hp + 1];
        sy[2 * hp] = h2f((unsigned short)(po[hp] & 0xffff)) * rv[2 * hp];
        sy[2 * hp + 1] = h2f((unsigned short)(po[hp] >> 16)) * rv[2 * hp + 1];
      }
#pragma unroll
      for (int g = 0; g < 8; g++) {
        float u0 = 0.f, u1 = 0.f;
#pragma unroll
        for (int h = 0; h < 8; h++) {
          u0 += cw[g * 8 + h] * sx[h];
          u1 += cw[g * 8 + h] * sy[h];
        }
        su[g] += u0 + u1;
        su2[g] += u0 * u0 + u1 * u1;
        *(unsigned*)&sU[g][mxn][mxm] = (unsigned)f2h(u0) | ((unsigned)f2h(u1) << 16);
      }
    }
    __syncthreads();  // sU ready
    {  // S@V for group w: A = sU[w], B = vT direct from global (L2-hot)
      f16x8 uf0 = *(const f16x8*)&sU[w][lm][lq * 8];
      f16x8 uf1 = *(const f16x8*)&sU[w][lm][32 + lq * 8];
#pragma unroll
      for (int j = 0; j < 4; j++) {
        const unsigned short* vp =
            vT + (((size_t)(b * Hh + w) * DH + 16 * j + lm) << 10) + it * 64 + lq * 8;
        f16x8 v0 = *(const f16x8*)vp;
        f16x8 v1 = *(const f16x8*)(vp + 32);
        oacc[j] = MFMA16(uf0, v0, oacc[j]);
        oacc[j] = MFMA16(uf1, v1, oacc[j]);
      }
    }
    __syncthreads();  // PV readers done before next mix overwrites sU
    if (it < 15) {
      c0 = nx0;
      c1 = nx1;
    }
  }
#pragma unroll
  for (int j = 0; j < 4; j++)
#pragma unroll
    for (int r = 0; r < 4; r++)
      O1[((size_t)(b * Hh + w) * Nn + n0 + lq * 4 + r) * DH + 16 * j + lm] = oacc[j][r];
#pragma unroll
  for (int g = 0; g < 8; g++) {
    float a = su[g], q = su2[g];
    for (int off = 32; off; off >>= 1) {
      a += __shfl_down(a, off);
      q += __shfl_down(q, off);
    }
    if (l == 0) {
      sRed[w][g] = a;
      sRed[w][8 + g] = q;
    }
  }
  __syncthreads();
  if (t < 16) {
    float s = 0.f;
#pragma unroll
    for (int ww = 0; ww < 8; ww++) s += sRed[ww][t];
    atomicAdd(&stats[t], s);
  }
}

// ---------------- K3: alpha/const ------------------------------------------
__global__ void k_alpha(const float* __restrict__ stats, const float* __restrict__ bn_gamma,
                        const float* __restrict__ bn_beta, float* __restrict__ ac) {
  const int g = threadIdx.x;
  if (g < 8) {
    const float cnt = (float)Bz * (float)Nn * (float)Nn;
    float Eu = stats[g] / cnt;
    float Eu2 = stats[8 + g] / cnt;
    float inv = rsqrtf(Eu2 - Eu * Eu + BN_EPS);
    float alpha = bn_gamma[g] * inv;
    ac[g] = alpha;
    ac[8 + g] = bn_beta[g] - Eu * alpha;
  }
}

// ---------------- K4: out = (alpha*O1 + c*vsum) @ w_out + b_out ------------
// k_o1aff fused into A-staging: k=g*64+dd, 16 consecutive k stay within one
// head g -> al/cc/vsum uniform per chunk. Reads O1 f32 directly (L3-hot).
__global__ __launch_bounds__(256) void k_out(const float* __restrict__ O1,
                                             const float* __restrict__ vsum,
                                             const float* __restrict__ ac,
                                             const unsigned short* __restrict__ WOT,
                                             const float* __restrict__ bout,
                                             float* __restrict__ out) {
  __shared__ unsigned short sA[128][40];
  __shared__ unsigned short sB[128][40];
  const int t = threadIdx.x;
  const int col0 = blockIdx.x * 128, row0 = blockIdx.y * 128;
  const int l = t & 63, w = t >> 6;
  const int wm = (w & 1) * 64, wn = (w >> 1) * 64;
  const int lm = l & 15, lq = l >> 4;
  const int srow = t >> 1, skc = (t & 1) * 16;
  const int b = row0 >> 10;
  const int nn = (row0 + srow) & 1023;
  f32x4 acc[4][4] = {};
  for (int k0 = 0; k0 < INNER; k0 += 32) {
    {  // A-stage with fused affine: O1hf = f2h(al*O1 + cc*vsum)
      const int k = k0 + skc;
      const int g = k >> 6, dd = k & 63;
      const float* src = O1 + ((size_t)(b * Hh + g) * Nn + nn) * DH + dd;
      const float* vs = vsum + (size_t)(b * Hh + g) * DH + dd;
      const float al = ac[g], cc = ac[8 + g];
      unsigned short us[16];
#pragma unroll
      for (int c4 = 0; c4 < 4; c4++) {
        float4 a = *(const float4*)(src + c4 * 4);
        float4 v = *(const float4*)(vs + c4 * 4);
        us[c4 * 4 + 0] = f2h(al * a.x + cc * v.x);
        us[c4 * 4 + 1] = f2h(al * a.y + cc * v.y);
        us[c4 * 4 + 2] = f2h(al * a.z + cc * v.z);
        us[c4 * 4 + 3] = f2h(al * a.w + cc * v.w);
      }
      *(uint4*)&sA[srow][skc] = *(uint4*)us;
      *(uint4*)&sA[srow][skc + 8] = *(uint4*)(us + 8);
    }
    {
      const unsigned short* srcB = WOT + (size_t)(col0 + srow) * INNER + k0 + skc;
      *(uint4*)&sB[srow][skc] = *(const uint4*)srcB;
      *(uint4*)&sB[srow][skc + 8] = *(const uint4*)(srcB + 8);
    }
    __syncthreads();
    f16x8 af[4], bfr[4];
#pragma unroll
    for (int i = 0; i < 4; i++) af[i] = *(const f16x8*)&sA[wm + 16 * i + lm][lq * 8];
#pragma unroll
    for (int j = 0; j < 4; j++) bfr[j] = *(const f16x8*)&sB[wn + 16 * j + lm][lq * 8];
#pragma unroll
    for (int i = 0; i < 4; i++)
#pragma unroll
      for (int j = 0; j < 4; j++) acc[i][j] = MFMA16(af[i], bfr[j], acc[i][j]);
    __syncthreads();
  }
#pragma unroll
  for (int j = 0; j < 4; j++) {
    const int col = col0 + wn + 16 * j + lm;
    const float bo = bout[col];
#pragma unroll
    for (int i = 0; i < 4; i++) {
      const int rbase = row0 + wm + 16 * i + lq * 4;
#pragma unroll
      for (int r = 0; r < 4; r++) out[(size_t)(rbase + r) * Dd + col] = acc[i][j][r] + bo;
    }
  }
}

extern "C" void kernel_launch(void* const* d_in, const int* in_sizes, int n_in,
                              void* d_out, int out_size, void* d_ws, size_t ws_size,
                              hipStream_t stream) {
  const float* x = (const float*)d_in[0];
  const float* w_qkv = (const float*)d_in[1];
  const float* conv_w = (const float*)d_in[2];
  // d_in[3] = conv_b : cancels in train-mode BN.
  const float* bn_gamma = (const float*)d_in[4];
  const float* bn_beta = (const float*)d_in[5];
  const float* w_out = (const float*)d_in[6];
  const float* b_out = (const float*)d_in[7];
  char* ws = (char*)d_ws;
  unsigned short* XB = (unsigned short*)(ws + WB_XB);
  unsigned short* QKV = (unsigned short*)(ws + WB_QKV);
  unsigned short* VT = (unsigned short*)(ws + WB_VT);
  unsigned short* SG = (unsigned short*)(ws + WB_SG);
  unsigned short* WQT = (unsigned short*)(ws + WB_WQT);
  unsigned short* WOT = (unsigned short*)(ws + WB_WOT);
  float* O1 = (float*)(ws + WB_O1);
  float* RSUM = (float*)(ws + WB_RSUM);
  float* VSUM = (float*)(ws + WB_VSUM);
  float* STATS = (float*)(ws + WB_STATS);
  float* AC = (float*)(ws + WB_AC);

  hipMemsetAsync(STATS, 0, 64, stream);
  hipMemsetAsync(RSUM, 0, 262144, stream);
  k_xbf<<<2048, 256, 0, stream>>>(x, XB);
  k_transpose<<<dim3(48, 16), 256, 0, stream>>>(w_qkv, WQT, 512, 1536);
  k_transpose<<<dim3(16, 16), 256, 0, stream>>>(w_out, WOT, 512, 512);
  k_qkv<<<dim3(12, 64), 256, 34816, stream>>>(XB, WQT, QKV, VT);
  k_vsum<<<64, 256, 0, stream>>>(VT, VSUM);
  k_sgen<<<dim3(8, 32, 2), 512, 0, stream>>>(QKV, SG, RSUM);
  k_mixsv<<<dim3(8, 64), 512, 0, stream>>>(SG, VT, RSUM, conv_w, O1, STATS);
  k_alpha<<<1, 64, 0, stream>>>(STATS, bn_gamma, bn_beta, AC);
  k_out<<<dim3(4, 64), 256, 0, stream>>>(O1, VSUM, AC, WOT, b_out, (float*)d_out);
}